// Round 2
// baseline (412.566 us; speedup 1.0000x reference)
//
#include <hip/hip_runtime.h>
#include <stdint.h>

// CrossAttention fused pipeline for MI355X (gfx950).
// R6: register-resident softmax attention.
//  - sigma-permuted K row loading: A-row m of QK tile nt reads kv row
//    32*(nt&1) + 8*(m>>2) + 4*(nt>>1) + (m&3).  After mfma(K,Q) each lane
//    holds S for kv = 32*hh + 8*quad + j (j=0..7) -> exp2 + v_cvt_pk_bf16_f32
//    produce the PV A-fragment DIRECTLY.  No P LDS, no barriers, no bank
//    conflicts; dep chain is MFMA -> exp2 -> cvt_pk -> MFMA.
//  - softmax scale (1/8)*log2e folded into Q-projection GEMM epilogue.
//  - __launch_bounds__(256,4): cap 128 VGPR -> 4 waves/SIMD.
//  - GEMM reverted to plain launch_bounds (R5's (256,3) risked spills).
// R5 kept: both attention directions merged into one 1536-block dispatch.
// R4 GEMM structure kept (BK=64, XOR-swizzled LDS, XCD m-partition).

#define DIM 1024
#define HEADS 16
#define DK 64
#define BATCH 8
#define NTXT 512
#define NVIS 1024

typedef __attribute__((ext_vector_type(8))) short bf16x8;
typedef __attribute__((ext_vector_type(4))) float f32x4;
typedef __attribute__((ext_vector_type(4))) unsigned short u16x4;
typedef __attribute__((ext_vector_type(4))) unsigned int u32x4;

__device__ inline unsigned short f2bf(float f) {
    unsigned u = __builtin_bit_cast(unsigned, f);
    u += 0x7fffu + ((u >> 16) & 1u);   // round-to-nearest-even
    return (unsigned short)(u >> 16);
}
__device__ inline f32x4 mfma16(bf16x8 a, bf16x8 b, f32x4 c) {
    return __builtin_amdgcn_mfma_f32_16x16x32_bf16(a, b, c, 0, 0, 0);
}
// async global->LDS, 16B per lane. LDS dest = wave-uniform base + lane*16.
__device__ inline void gl_lds16(const unsigned short* gp, unsigned short* lp) {
    const auto* g1 = reinterpret_cast<const __attribute__((address_space(1))) unsigned int*>(
        reinterpret_cast<uintptr_t>(gp));
    auto* l3 = reinterpret_cast<__attribute__((address_space(3))) unsigned int*>(
        reinterpret_cast<uintptr_t>(lp));
    __builtin_amdgcn_global_load_lds(g1, l3, 16, 0, 0);
}

// ---------------------------------------------------------------- weights cvt
struct WPtrs { const float* w[6]; };

__global__ __launch_bounds__(256) void cvt_w_kernel(WPtrs p, unsigned short* __restrict__ out) {
    int g = blockIdx.y;
    int i = blockIdx.x * 256 + threadIdx.x;          // groups of 4 floats
    float4 v = ((const float4*)p.w[g])[i];
    u16x4 o;
    o[0] = f2bf(v.x); o[1] = f2bf(v.y); o[2] = f2bf(v.z); o[3] = f2bf(v.w);
    *(u16x4*)(out + (size_t)g * (DIM * DIM) + (size_t)i * 4) = o;
}

// ------------------------------------------------------- layernorm + residual
__global__ __launch_bounds__(256) void ln_copy_kernel(
        const float* __restrict__ x, const float* __restrict__ g,
        const float* __restrict__ bta, unsigned short* __restrict__ xn,
        float* __restrict__ res) {
    int row = blockIdx.x;
    int tid = threadIdx.x;
    const float4* xr = (const float4*)(x + (size_t)row * DIM);
    float4 v = xr[tid];
    float s = v.x + v.y + v.z + v.w;
    float ss = v.x * v.x + v.y * v.y + v.z * v.z + v.w * v.w;
#pragma unroll
    for (int m = 1; m < 64; m <<= 1) { s += __shfl_xor(s, m); ss += __shfl_xor(ss, m); }
    __shared__ float red[8];
    int wave = tid >> 6, lane = tid & 63;
    if (lane == 0) { red[wave] = s; red[4 + wave] = ss; }
    __syncthreads();
    s = red[0] + red[1] + red[2] + red[3];
    ss = red[4] + red[5] + red[6] + red[7];
    float mu = s * (1.0f / DIM);
    float var = ss * (1.0f / DIM) - mu * mu;
    float rinv = rsqrtf(var + 1e-5f);
    float4 gv = ((const float4*)g)[tid];
    float4 bv = ((const float4*)bta)[tid];
    ((float4*)(res + (size_t)row * DIM))[tid] = v;    // residual passthrough
    u16x4 o;
    o[0] = f2bf((v.x - mu) * rinv * gv.x + bv.x);
    o[1] = f2bf((v.y - mu) * rinv * gv.y + bv.y);
    o[2] = f2bf((v.z - mu) * rinv * gv.z + bv.z);
    o[3] = f2bf((v.w - mu) * rinv * gv.w + bv.w);
    *(u16x4*)(xn + (size_t)row * DIM + tid * 4) = o;
}

// -------------------------------------------------------------- fused QKV GEMM
// C[m][n] = sum_k A[m][k] * W[n][k] + bias[n]   (NT layout)
// g in {2,5} (V projections) write TRANSPOSED: Vt[b][h][d][npos]
// g in {0,3} (Q projections) are pre-scaled by (1/8)*log2(e) for softmax.
struct GemmParams {
    const unsigned short* A[2];      // [0]=t_norm (M=4096), [1]=v_norm (M=8192)
    const unsigned short* W;         // 6 contiguous bf16 weight matrices
    const float* bias[6];
    unsigned short* out[6];          // out[2],out[5] are transposed-V buffers
};

__global__ __launch_bounds__(256) void gemm_qkv_kernel(GemmParams P) {
    int bid = blockIdx.x;
    int xcd = bid & 7;
    int idx = bid >> 3;                 // 0..287 per XCD
    int g, tm, tn;
    if (idx < 96) {                     // text: 24 columns x 4 m-tiles
        int col = idx >> 2, mi = idx & 3;
        g = col >> 3; tn = col & 7; tm = xcd * 4 + mi;
    } else {                            // vision: 24 columns x 8 m-tiles
        int j = idx - 96;
        int col = j >> 3, mi = j & 7;
        g = 3 + (col >> 3); tn = col & 7; tm = xcd * 8 + mi;
    }
    const unsigned short* A = P.A[g < 3 ? 0 : 1];
    const unsigned short* Ap = A + (size_t)tm * 128 * DIM;
    const unsigned short* Wp = P.W + (size_t)g * (DIM * DIM) + (size_t)tn * 128 * DIM;

    __shared__ __align__(16) unsigned short As[128][64];
    __shared__ __align__(16) unsigned short Bs[128][64];

    int tid = threadIdx.x;
    int wave = tid >> 6, lane = tid & 63;
    int wm = (wave & 1) * 64, wn = (wave >> 1) * 64;
    int col16 = lane & 15, quad = lane >> 4;

    // staging: 1024 16B-slots per buffer; slot s -> row=s>>3, pos=s&7;
    // global chunk fetched into pos p of row r is c = p ^ (r&7).
    int sbase = wave * 64 + lane;
    size_t ga[4];
    unsigned short* lA[4];
    unsigned short* lB[4];
#pragma unroll
    for (int i = 0; i < 4; i++) {
        int s = sbase + i * 256;
        int row = s >> 3;
        int c = (s & 7) ^ (row & 7);
        ga[i] = (size_t)row * DIM + (size_t)c * 8;
        lA[i] = &As[0][0] + (size_t)s * 8;
        lB[i] = &Bs[0][0] + (size_t)s * 8;
    }

    f32x4 zero = {0.f, 0.f, 0.f, 0.f};
    f32x4 acc[4][4];
#pragma unroll
    for (int i = 0; i < 4; i++)
#pragma unroll
        for (int j = 0; j < 4; j++) acc[i][j] = zero;

    for (int k0 = 0; k0 < DIM; k0 += 64) {
        __syncthreads();                                  // WAR on LDS
#pragma unroll
        for (int i = 0; i < 4; i++) {
            gl_lds16(Ap + ga[i] + k0, lA[i]);
            gl_lds16(Wp + ga[i] + k0, lB[i]);
        }
        __syncthreads();                                  // drain + RAW
#pragma unroll
        for (int ks = 0; ks < 2; ks++) {
            bf16x8 af[4], bfr[4];
#pragma unroll
            for (int mi = 0; mi < 4; mi++) {
                int r = wm + mi * 16 + col16;
                int p = (ks * 4 + quad) ^ (r & 7);
                af[mi] = *(const bf16x8*)&As[r][p * 8];
            }
#pragma unroll
            for (int ni = 0; ni < 4; ni++) {
                int r = wn + ni * 16 + col16;
                int p = (ks * 4 + quad) ^ (r & 7);
                bfr[ni] = *(const bf16x8*)&Bs[r][p * 8];
            }
#pragma unroll
            for (int mi = 0; mi < 4; mi++)
#pragma unroll
                for (int ni = 0; ni < 4; ni++)
                    acc[mi][ni] = mfma16(af[mi], bfr[ni], acc[mi][ni]);
        }
    }

    const float* bias = P.bias[g];
    unsigned short* out = P.out[g];
    // Q projections carry the softmax scale so attention can use raw exp2.
    float qs = (g == 0 || g == 3) ? 0.18033688f : 1.0f;   // (1/8)*log2(e)
    float bv[4];
#pragma unroll
    for (int ni = 0; ni < 4; ni++) bv[ni] = bias[tn * 128 + wn + ni * 16 + col16];

    if (g == 2 || g == 5) {
        int N = (g == 2) ? NTXT : NVIS;
#pragma unroll
        for (int mi = 0; mi < 4; mi++) {
            int row0 = tm * 128 + wm + mi * 16 + quad * 4;
            int b = row0 / N;
            int npos = row0 - b * N;
#pragma unroll
            for (int ni = 0; ni < 4; ni++) {
                int col = tn * 128 + wn + ni * 16 + col16;
                int h = col >> 6, d = col & 63;
                u16x4 pk;
#pragma unroll
                for (int reg = 0; reg < 4; reg++) pk[reg] = f2bf(acc[mi][ni][reg] + bv[ni]);
                *(u16x4*)(out + ((size_t)((b * HEADS + h) * DK + d)) * N + npos) = pk;
            }
        }
    } else {
#pragma unroll
        for (int mi = 0; mi < 4; mi++) {
#pragma unroll
            for (int reg = 0; reg < 4; reg++) {
                int row = tm * 128 + wm + mi * 16 + quad * 4 + reg;
#pragma unroll
                for (int ni = 0; ni < 4; ni++) {
                    out[(size_t)row * DIM + tn * 128 + wn + ni * 16 + col16] =
                        f2bf((acc[mi][ni][reg] + bv[ni]) * qs);
                }
            }
        }
    }
}

// ------------------------------------------------------- flash cross-attention
// ONE dispatch, both directions.  Per wave: 32 q-rows, iterate kv in tiles of
// 64.  Swapped QK^T with sigma-permuted K rows:
//   A-row m of tile nt reads kv = 32*(nt&1) + 8*(m>>2) + 4*(nt>>1) + (m&3)
// so lane (col16, quad) exits QK holding S[q=col16][kv = 32*hh + 8*quad + j],
// which after exp2 + v_cvt_pk_bf16_f32 IS the PV A-fragment (kv-chunk quad*8
// within the K=32 step).  P never touches LDS; kernel has no LDS at all.
// Q is pre-scaled by (1/8)*log2e in the GEMM, so p = exp2(S) directly.
__global__ __launch_bounds__(256, 4) void attn_kernel(
        const unsigned short* __restrict__ Q1, const unsigned short* __restrict__ K1,
        const unsigned short* __restrict__ V1t, float* __restrict__ O1,
        const unsigned short* __restrict__ Q2, const unsigned short* __restrict__ K2,
        const unsigned short* __restrict__ V2t, float* __restrict__ O2) {
    int bid = blockIdx.x;
    const unsigned short* Q; const unsigned short* K; const unsigned short* Vt;
    float* Out; int Nq, Nkv;
    if (bid < 512) { Q = Q1; K = K1; Vt = V1t; Out = O1; Nq = NTXT; Nkv = NVIS; }
    else { bid -= 512; Q = Q2; K = K2; Vt = V2t; Out = O2; Nq = NVIS; Nkv = NTXT; }
    int bh = bid & 127;                 // 128 (b,h) pairs
    int qt = bid >> 7;                  // q-tile of 128 rows
    int b = bh >> 4, h = bh & 15;
    int tid = threadIdx.x;
    int wave = tid >> 6, lane = tid & 63;
    int col16 = lane & 15, quad = lane >> 4;

    const unsigned short* qbase =
        Q + ((size_t)(b * Nq + qt * 128 + wave * 32 + col16)) * DIM + h * DK;
    bf16x8 qa[2][2];
#pragma unroll
    for (int mg = 0; mg < 2; mg++) {
        qa[mg][0] = *(const bf16x8*)(qbase + (size_t)mg * 16 * DIM + quad * 8);
        qa[mg][1] = *(const bf16x8*)(qbase + (size_t)mg * 16 * DIM + 32 + quad * 8);
    }

    // sigma row base for this lane: 8*(col16>>2) + (col16&3)
    int r0 = ((col16 >> 2) << 3) + (col16 & 3);
    const unsigned short* Kl = K + ((size_t)b * Nkv + r0) * DIM + h * DK + quad * 8;
    const unsigned short* Vl =
        Vt + (size_t)(b * HEADS + h) * DK * Nkv + (size_t)col16 * Nkv + quad * 8;

    f32x4 zero = {0.f, 0.f, 0.f, 0.f};
    f32x4 o[2][4];
#pragma unroll
    for (int mg = 0; mg < 2; mg++)
#pragma unroll
        for (int d = 0; d < 4; d++) o[mg][d] = zero;
    float lsum[2] = {0.f, 0.f};

    for (int nb = 0; nb < Nkv; nb += 64) {
#pragma unroll
        for (int hh = 0; hh < 2; hh++) {
            // K fragments: nt=hh (kv base 32*hh + r0) and nt=hh+2 (+4 rows)
            const unsigned short* kp = Kl + (size_t)(nb + 32 * hh) * DIM;
            bf16x8 ka0 = *(const bf16x8*)(kp);
            bf16x8 ka1 = *(const bf16x8*)(kp + 32);
            bf16x8 kb0 = *(const bf16x8*)(kp + (size_t)4 * DIM);
            bf16x8 kb1 = *(const bf16x8*)(kp + (size_t)4 * DIM + 32);
            // V fragments for this kv half (B-rows d*16+col16, k=npos chunk)
            bf16x8 vf[4];
#pragma unroll
            for (int d = 0; d < 4; d++)
                vf[d] = *(const bf16x8*)(Vl + (size_t)(d * 16) * Nkv + nb + hh * 32);

#pragma unroll
            for (int mg = 0; mg < 2; mg++) {
                f32x4 ca = zero, cb = zero;
                ca = mfma16(ka0, qa[mg][0], ca);
                ca = mfma16(ka1, qa[mg][1], ca);
                cb = mfma16(kb0, qa[mg][0], cb);
                cb = mfma16(kb1, qa[mg][1], cb);
                float p0 = exp2f(ca[0]), p1 = exp2f(ca[1]);
                float p2 = exp2f(ca[2]), p3 = exp2f(ca[3]);
                float p4 = exp2f(cb[0]), p5 = exp2f(cb[1]);
                float p6 = exp2f(cb[2]), p7 = exp2f(cb[3]);
                lsum[mg] += ((p0 + p1) + (p2 + p3)) + ((p4 + p5) + (p6 + p7));
                unsigned int w0, w1, w2, w3;
                asm("v_cvt_pk_bf16_f32 %0, %1, %2" : "=v"(w0) : "v"(p0), "v"(p1));
                asm("v_cvt_pk_bf16_f32 %0, %1, %2" : "=v"(w1) : "v"(p2), "v"(p3));
                asm("v_cvt_pk_bf16_f32 %0, %1, %2" : "=v"(w2) : "v"(p4), "v"(p5));
                asm("v_cvt_pk_bf16_f32 %0, %1, %2" : "=v"(w3) : "v"(p6), "v"(p7));
                u32x4 pw = {w0, w1, w2, w3};
                bf16x8 pf = __builtin_bit_cast(bf16x8, pw);
#pragma unroll
                for (int d = 0; d < 4; d++) o[mg][d] = mfma16(pf, vf[d], o[mg][d]);
            }
        }
    }

    // epilogue: denom for q-row col16 lives per-lane; butterfly over quads,
    // then pull denom[quad*4+reg] for the C-layout output rows.
#pragma unroll
    for (int mg = 0; mg < 2; mg++) {
        float l = lsum[mg];
        l += __shfl_xor(l, 16);
        l += __shfl_xor(l, 32);
#pragma unroll
        for (int reg = 0; reg < 4; reg++) {
            float inv = 1.0f / __shfl(l, quad * 4 + reg);
            int nrow = qt * 128 + wave * 32 + mg * 16 + quad * 4 + reg;
            float* op = Out + ((size_t)(b * Nq + nrow)) * DIM + h * DK;
#pragma unroll
            for (int d = 0; d < 4; d++) op[d * 16 + col16] = o[mg][d][reg] * inv;
        }
    }
}

// -------------------------------------------------------------------- launch
extern "C" void kernel_launch(void* const* d_in, const int* in_sizes, int n_in,
                              void* d_out, int out_size, void* d_ws, size_t ws_size,
                              hipStream_t stream) {
    const float* text   = (const float*)d_in[0];
    const float* vision = (const float*)d_in[1];
    const float* n1g = (const float*)d_in[2];
    const float* n1b = (const float*)d_in[3];
    const float* n2g = (const float*)d_in[4];
    const float* n2b = (const float*)d_in[5];
    const float* W[6];
    const float* bias[6];
    for (int i = 0; i < 6; i++) {
        W[i]    = (const float*)d_in[6 + 2 * i];
        bias[i] = (const float*)d_in[7 + 2 * i];
    }

    float* out = (float*)d_out;
    float* a1   = out;                 // (8,512,1024)
    float* a2   = out + 4194304;       // (8,1024,1024)
    float* tres = out + 12582912;      // (8,512,1024)
    float* vres = out + 16777216;      // (8,1024,1024)

    char* ws = (char*)d_ws;
    unsigned short* Wc  = (unsigned short*)(ws);              // 12.0 MB
    unsigned short* tno = (unsigned short*)(ws + 12582912);   //  8.0 MB
    unsigned short* vno = (unsigned short*)(ws + 20971520);   // 16.0 MB
    unsigned short* tq  = (unsigned short*)(ws + 37748736);
    unsigned short* tk  = (unsigned short*)(ws + 46137344);
    unsigned short* tvT = (unsigned short*)(ws + 54525952);   // transposed
    unsigned short* vq  = (unsigned short*)(ws + 62914560);
    unsigned short* vk  = (unsigned short*)(ws + 79691776);
    unsigned short* vvT = (unsigned short*)(ws + 96468992);   // transposed

    WPtrs wp;
    for (int i = 0; i < 6; i++) wp.w[i] = W[i];
    cvt_w_kernel<<<dim3(1024, 6), 256, 0, stream>>>(wp, Wc);
    ln_copy_kernel<<<4096, 256, 0, stream>>>(text, n1g, n1b, tno, tres);
    ln_copy_kernel<<<8192, 256, 0, stream>>>(vision, n2g, n2b, vno, vres);

    GemmParams gp;
    gp.A[0] = tno; gp.A[1] = vno; gp.W = Wc;
    for (int i = 0; i < 6; i++) gp.bias[i] = bias[i];
    gp.out[0] = tq; gp.out[1] = tk; gp.out[2] = tvT;
    gp.out[3] = vq; gp.out[4] = vk; gp.out[5] = vvT;
    gemm_qkv_kernel<<<2304, 256, 0, stream>>>(gp);

    // both cross-attentions in one dispatch (independent jobs, overlap them)
    attn_kernel<<<1536, 256, 0, stream>>>(tq, vk, vvT, a1, vq, tk, tvT, a2);
}

// Round 3
// 324.670 us; speedup vs baseline: 1.2707x; 1.2707x over previous
//
#include <hip/hip_runtime.h>
#include <stdint.h>

// CrossAttention fused pipeline for MI355X (gfx950).
// R7: LDS-staged K/V attention (the 4 waves of a block share identical K/V
//   tiles; R6 re-loaded them per-wave with scattered global loads = exposed
//   latency, 4.9K cyc/iter wall vs 1.3K issue).
//  - Fragment-major LDS: frag f at base+f*1KB, lane data at lane*16B == the
//    linear layout global_load_lds forces; sigma-permutation applied on the
//    per-lane GLOBAL source address (linear-dest + permuted-source rule).
//  - Depth-1 double buffer, one __syncthreads per kv-tile:
//    STAGE(buf^1,t+1); COMPUTE(buf); barrier.  4 gl_lds16/wave/tile +
//    16 dense ds_read_b128 replace 16 scattered global loads.
//  - exp2 via __builtin_amdgcn_exp2f (drop ocml wrapper VALU).
//  - GEMM: __launch_bounds__(256,3) restored (R1 evidence: no spill-blowup,
//    total was ~18us better than R2's revert).
// R6 kept: register-resident softmax (sigma-permuted K rows -> QK C-layout
//   IS the PV A-fragment after exp2+cvt_pk), softmax scale folded into Q GEMM.
// R5 kept: both attention directions in one 1536-block dispatch.
// R4 GEMM structure kept (BK=64, XOR-swizzled LDS, XCD m-partition).

#define DIM 1024
#define HEADS 16
#define DK 64
#define BATCH 8
#define NTXT 512
#define NVIS 1024

typedef __attribute__((ext_vector_type(8))) short bf16x8;
typedef __attribute__((ext_vector_type(4))) float f32x4;
typedef __attribute__((ext_vector_type(4))) unsigned short u16x4;
typedef __attribute__((ext_vector_type(4))) unsigned int u32x4;

__device__ inline unsigned short f2bf(float f) {
    unsigned u = __builtin_bit_cast(unsigned, f);
    u += 0x7fffu + ((u >> 16) & 1u);   // round-to-nearest-even
    return (unsigned short)(u >> 16);
}
__device__ inline f32x4 mfma16(bf16x8 a, bf16x8 b, f32x4 c) {
    return __builtin_amdgcn_mfma_f32_16x16x32_bf16(a, b, c, 0, 0, 0);
}
// async global->LDS, 16B per lane. LDS dest = wave-uniform base + lane*16.
__device__ inline void gl_lds16(const unsigned short* gp, unsigned short* lp) {
    const auto* g1 = reinterpret_cast<const __attribute__((address_space(1))) unsigned int*>(
        reinterpret_cast<uintptr_t>(gp));
    auto* l3 = reinterpret_cast<__attribute__((address_space(3))) unsigned int*>(
        reinterpret_cast<uintptr_t>(lp));
    __builtin_amdgcn_global_load_lds(g1, l3, 16, 0, 0);
}

// ---------------------------------------------------------------- weights cvt
struct WPtrs { const float* w[6]; };

__global__ __launch_bounds__(256) void cvt_w_kernel(WPtrs p, unsigned short* __restrict__ out) {
    int g = blockIdx.y;
    int i = blockIdx.x * 256 + threadIdx.x;          // groups of 4 floats
    float4 v = ((const float4*)p.w[g])[i];
    u16x4 o;
    o[0] = f2bf(v.x); o[1] = f2bf(v.y); o[2] = f2bf(v.z); o[3] = f2bf(v.w);
    *(u16x4*)(out + (size_t)g * (DIM * DIM) + (size_t)i * 4) = o;
}

// ------------------------------------------------------- layernorm + residual
__global__ __launch_bounds__(256) void ln_copy_kernel(
        const float* __restrict__ x, const float* __restrict__ g,
        const float* __restrict__ bta, unsigned short* __restrict__ xn,
        float* __restrict__ res) {
    int row = blockIdx.x;
    int tid = threadIdx.x;
    const float4* xr = (const float4*)(x + (size_t)row * DIM);
    float4 v = xr[tid];
    float s = v.x + v.y + v.z + v.w;
    float ss = v.x * v.x + v.y * v.y + v.z * v.z + v.w * v.w;
#pragma unroll
    for (int m = 1; m < 64; m <<= 1) { s += __shfl_xor(s, m); ss += __shfl_xor(ss, m); }
    __shared__ float red[8];
    int wave = tid >> 6, lane = tid & 63;
    if (lane == 0) { red[wave] = s; red[4 + wave] = ss; }
    __syncthreads();
    s = red[0] + red[1] + red[2] + red[3];
    ss = red[4] + red[5] + red[6] + red[7];
    float mu = s * (1.0f / DIM);
    float var = ss * (1.0f / DIM) - mu * mu;
    float rinv = rsqrtf(var + 1e-5f);
    float4 gv = ((const float4*)g)[tid];
    float4 bv = ((const float4*)bta)[tid];
    ((float4*)(res + (size_t)row * DIM))[tid] = v;    // residual passthrough
    u16x4 o;
    o[0] = f2bf((v.x - mu) * rinv * gv.x + bv.x);
    o[1] = f2bf((v.y - mu) * rinv * gv.y + bv.y);
    o[2] = f2bf((v.z - mu) * rinv * gv.z + bv.z);
    o[3] = f2bf((v.w - mu) * rinv * gv.w + bv.w);
    *(u16x4*)(xn + (size_t)row * DIM + tid * 4) = o;
}

// -------------------------------------------------------------- fused QKV GEMM
// C[m][n] = sum_k A[m][k] * W[n][k] + bias[n]   (NT layout)
// g in {2,5} (V projections) write TRANSPOSED: Vt[b][h][d][npos]
// g in {0,3} (Q projections) are pre-scaled by (1/8)*log2(e) for softmax.
struct GemmParams {
    const unsigned short* A[2];      // [0]=t_norm (M=4096), [1]=v_norm (M=8192)
    const unsigned short* W;         // 6 contiguous bf16 weight matrices
    const float* bias[6];
    unsigned short* out[6];          // out[2],out[5] are transposed-V buffers
};

__global__ __launch_bounds__(256, 3) void gemm_qkv_kernel(GemmParams P) {
    int bid = blockIdx.x;
    int xcd = bid & 7;
    int idx = bid >> 3;                 // 0..287 per XCD
    int g, tm, tn;
    if (idx < 96) {                     // text: 24 columns x 4 m-tiles
        int col = idx >> 2, mi = idx & 3;
        g = col >> 3; tn = col & 7; tm = xcd * 4 + mi;
    } else {                            // vision: 24 columns x 8 m-tiles
        int j = idx - 96;
        int col = j >> 3, mi = j & 7;
        g = 3 + (col >> 3); tn = col & 7; tm = xcd * 8 + mi;
    }
    const unsigned short* A = P.A[g < 3 ? 0 : 1];
    const unsigned short* Ap = A + (size_t)tm * 128 * DIM;
    const unsigned short* Wp = P.W + (size_t)g * (DIM * DIM) + (size_t)tn * 128 * DIM;

    __shared__ __align__(16) unsigned short As[128][64];
    __shared__ __align__(16) unsigned short Bs[128][64];

    int tid = threadIdx.x;
    int wave = tid >> 6, lane = tid & 63;
    int wm = (wave & 1) * 64, wn = (wave >> 1) * 64;
    int col16 = lane & 15, quad = lane >> 4;

    // staging: 1024 16B-slots per buffer; slot s -> row=s>>3, pos=s&7;
    // global chunk fetched into pos p of row r is c = p ^ (r&7).
    int sbase = wave * 64 + lane;
    size_t ga[4];
    unsigned short* lA[4];
    unsigned short* lB[4];
#pragma unroll
    for (int i = 0; i < 4; i++) {
        int s = sbase + i * 256;
        int row = s >> 3;
        int c = (s & 7) ^ (row & 7);
        ga[i] = (size_t)row * DIM + (size_t)c * 8;
        lA[i] = &As[0][0] + (size_t)s * 8;
        lB[i] = &Bs[0][0] + (size_t)s * 8;
    }

    f32x4 zero = {0.f, 0.f, 0.f, 0.f};
    f32x4 acc[4][4];
#pragma unroll
    for (int i = 0; i < 4; i++)
#pragma unroll
        for (int j = 0; j < 4; j++) acc[i][j] = zero;

    for (int k0 = 0; k0 < DIM; k0 += 64) {
        __syncthreads();                                  // WAR on LDS
#pragma unroll
        for (int i = 0; i < 4; i++) {
            gl_lds16(Ap + ga[i] + k0, lA[i]);
            gl_lds16(Wp + ga[i] + k0, lB[i]);
        }
        __syncthreads();                                  // drain + RAW
#pragma unroll
        for (int ks = 0; ks < 2; ks++) {
            bf16x8 af[4], bfr[4];
#pragma unroll
            for (int mi = 0; mi < 4; mi++) {
                int r = wm + mi * 16 + col16;
                int p = (ks * 4 + quad) ^ (r & 7);
                af[mi] = *(const bf16x8*)&As[r][p * 8];
            }
#pragma unroll
            for (int ni = 0; ni < 4; ni++) {
                int r = wn + ni * 16 + col16;
                int p = (ks * 4 + quad) ^ (r & 7);
                bfr[ni] = *(const bf16x8*)&Bs[r][p * 8];
            }
#pragma unroll
            for (int mi = 0; mi < 4; mi++)
#pragma unroll
                for (int ni = 0; ni < 4; ni++)
                    acc[mi][ni] = mfma16(af[mi], bfr[ni], acc[mi][ni]);
        }
    }

    const float* bias = P.bias[g];
    unsigned short* out = P.out[g];
    // Q projections carry the softmax scale so attention can use raw exp2.
    float qs = (g == 0 || g == 3) ? 0.18033688f : 1.0f;   // (1/8)*log2(e)
    float bv[4];
#pragma unroll
    for (int ni = 0; ni < 4; ni++) bv[ni] = bias[tn * 128 + wn + ni * 16 + col16];

    if (g == 2 || g == 5) {
        int N = (g == 2) ? NTXT : NVIS;
#pragma unroll
        for (int mi = 0; mi < 4; mi++) {
            int row0 = tm * 128 + wm + mi * 16 + quad * 4;
            int b = row0 / N;
            int npos = row0 - b * N;
#pragma unroll
            for (int ni = 0; ni < 4; ni++) {
                int col = tn * 128 + wn + ni * 16 + col16;
                int h = col >> 6, d = col & 63;
                u16x4 pk;
#pragma unroll
                for (int reg = 0; reg < 4; reg++) pk[reg] = f2bf(acc[mi][ni][reg] + bv[ni]);
                *(u16x4*)(out + ((size_t)((b * HEADS + h) * DK + d)) * N + npos) = pk;
            }
        }
    } else {
#pragma unroll
        for (int mi = 0; mi < 4; mi++) {
#pragma unroll
            for (int reg = 0; reg < 4; reg++) {
                int row = tm * 128 + wm + mi * 16 + quad * 4 + reg;
#pragma unroll
                for (int ni = 0; ni < 4; ni++) {
                    out[(size_t)row * DIM + tn * 128 + wn + ni * 16 + col16] =
                        f2bf((acc[mi][ni][reg] + bv[ni]) * qs);
                }
            }
        }
    }
}

// ------------------------------------------------------- flash cross-attention
// ONE dispatch, both directions.  Block = 4 waves x 32 q-rows, one (b,h,qtile).
// The 4 waves share identical K/V kv-tiles -> staged ONCE per block into LDS,
// fragment-major ([frag][lane]: frag f at base+f*1KB, lane's 16B at lane*16),
// sigma-permutation applied on the per-lane GLOBAL source address so the
// forced-linear global_load_lds destination lands each lane's MFMA fragment
// exactly where a dense lane-linear ds_read_b128 picks it up.
// K frag f = hh*4 + pair*2 + kh : row 32*hh + 4*pair + r0(col16), col kh*32+quad*8
// V frag f = hh*4 + d           : Vt row d*16+col16, kv col hh*32+quad*8
// Depth-1 double buffer: STAGE(buf^1,t+1); COMPUTE(buf); __syncthreads().
__global__ __launch_bounds__(256, 4) void attn_kernel(
        const unsigned short* __restrict__ Q1, const unsigned short* __restrict__ K1,
        const unsigned short* __restrict__ V1t, float* __restrict__ O1,
        const unsigned short* __restrict__ Q2, const unsigned short* __restrict__ K2,
        const unsigned short* __restrict__ V2t, float* __restrict__ O2) {
    int bid = blockIdx.x;
    const unsigned short* Q; const unsigned short* K; const unsigned short* Vt;
    float* Out; int Nq, Nkv;
    if (bid < 512) { Q = Q1; K = K1; Vt = V1t; Out = O1; Nq = NTXT; Nkv = NVIS; }
    else { bid -= 512; Q = Q2; K = K2; Vt = V2t; Out = O2; Nq = NVIS; Nkv = NTXT; }
    int bh = bid & 127;                 // 128 (b,h) pairs
    int qt = bid >> 7;                  // q-tile of 128 rows
    int b = bh >> 4, h = bh & 15;
    int tid = threadIdx.x;
    int wave = tid >> 6, lane = tid & 63;
    int col16 = lane & 15, quad = lane >> 4;

    // [parity][K=0/V=1][frag 0..7][512 shorts = 1KB]; 32KB total.
    __shared__ __align__(16) unsigned short KV[2][2][8][512];

    const unsigned short* qbase =
        Q + ((size_t)(b * Nq + qt * 128 + wave * 32 + col16)) * DIM + h * DK;
    bf16x8 qa[2][2];
#pragma unroll
    for (int mg = 0; mg < 2; mg++) {
        qa[mg][0] = *(const bf16x8*)(qbase + (size_t)mg * 16 * DIM + quad * 8);
        qa[mg][1] = *(const bf16x8*)(qbase + (size_t)mg * 16 * DIM + 32 + quad * 8);
    }

    // sigma row base for this lane: 8*(col16>>2) + (col16&3)
    int r0 = ((col16 >> 2) << 3) + (col16 & 3);

    // This wave stages K frags {2w,2w+1} and V frags {2w,2w+1}:
    //   K: hh = w>>1, pair = w&1, kh = 0/1
    //   V: hh = w>>1, d = 2*(w&1) + 0/1
    int whh = wave >> 1, wpr = wave & 1;
    const unsigned short* Ksrc =
        K + ((size_t)b * Nkv + 32 * whh + 4 * wpr + r0) * DIM + h * DK + quad * 8;
    const unsigned short* Vsrc =
        Vt + (size_t)(b * HEADS + h) * DK * Nkv
           + (size_t)(2 * wpr * 16 + col16) * Nkv + 32 * whh + quad * 8;
    unsigned short* ldsK0 = &KV[0][0][2 * wave][0];
    unsigned short* ldsK1 = &KV[0][0][2 * wave + 1][0];
    unsigned short* ldsV0 = &KV[0][1][2 * wave][0];
    unsigned short* ldsV1 = &KV[0][1][2 * wave + 1][0];
    const int PSTRIDE = 2 * 8 * 512;    // shorts per parity (16KB)

    f32x4 zero = {0.f, 0.f, 0.f, 0.f};
    f32x4 o[2][4];
#pragma unroll
    for (int mg = 0; mg < 2; mg++)
#pragma unroll
        for (int d = 0; d < 4; d++) o[mg][d] = zero;
    float lsum[2] = {0.f, 0.f};

    auto STAGE = [&](int p, int nb) {
        const unsigned short* ks = Ksrc + (size_t)nb * DIM;
        const unsigned short* vs = Vsrc + nb;
        int po = p * PSTRIDE;
        gl_lds16(ks,            ldsK0 + po);
        gl_lds16(ks + 32,       ldsK1 + po);
        gl_lds16(vs,            ldsV0 + po);
        gl_lds16(vs + 16 * Nkv, ldsV1 + po);
    };

    auto COMPUTE = [&](int p) {
        const unsigned short* base = &KV[p][0][0][0] + lane * 8;
#pragma unroll
        for (int hh = 0; hh < 2; hh++) {
            bf16x8 ka0 = *(const bf16x8*)(base + (hh * 4 + 0) * 512);
            bf16x8 ka1 = *(const bf16x8*)(base + (hh * 4 + 1) * 512);
            bf16x8 kb0 = *(const bf16x8*)(base + (hh * 4 + 2) * 512);
            bf16x8 kb1 = *(const bf16x8*)(base + (hh * 4 + 3) * 512);
            bf16x8 vf[4];
#pragma unroll
            for (int d = 0; d < 4; d++)
                vf[d] = *(const bf16x8*)(base + 4096 + (hh * 4 + d) * 512);
#pragma unroll
            for (int mg = 0; mg < 2; mg++) {
                f32x4 ca = zero, cb = zero;
                ca = mfma16(ka0, qa[mg][0], ca);
                ca = mfma16(ka1, qa[mg][1], ca);
                cb = mfma16(kb0, qa[mg][0], cb);
                cb = mfma16(kb1, qa[mg][1], cb);
                float p0 = __builtin_amdgcn_exp2f(ca[0]);
                float p1 = __builtin_amdgcn_exp2f(ca[1]);
                float p2 = __builtin_amdgcn_exp2f(ca[2]);
                float p3 = __builtin_amdgcn_exp2f(ca[3]);
                float p4 = __builtin_amdgcn_exp2f(cb[0]);
                float p5 = __builtin_amdgcn_exp2f(cb[1]);
                float p6 = __builtin_amdgcn_exp2f(cb[2]);
                float p7 = __builtin_amdgcn_exp2f(cb[3]);
                lsum[mg] += ((p0 + p1) + (p2 + p3)) + ((p4 + p5) + (p6 + p7));
                unsigned int w0, w1, w2, w3;
                asm("v_cvt_pk_bf16_f32 %0, %1, %2" : "=v"(w0) : "v"(p0), "v"(p1));
                asm("v_cvt_pk_bf16_f32 %0, %1, %2" : "=v"(w1) : "v"(p2), "v"(p3));
                asm("v_cvt_pk_bf16_f32 %0, %1, %2" : "=v"(w2) : "v"(p4), "v"(p5));
                asm("v_cvt_pk_bf16_f32 %0, %1, %2" : "=v"(w3) : "v"(p6), "v"(p7));
                u32x4 pw = {w0, w1, w2, w3};
                bf16x8 pf = __builtin_bit_cast(bf16x8, pw);
#pragma unroll
                for (int d = 0; d < 4; d++) o[mg][d] = mfma16(pf, vf[d], o[mg][d]);
            }
        }
    };

    int NT = Nkv >> 6;
    STAGE(0, 0);
    __syncthreads();                       // drain prologue stage
    int par = 0;
    for (int t = 0; t + 1 < NT; t++) {
        STAGE(par ^ 1, (t + 1) << 6);      // prefetch next tile (async)
        COMPUTE(par);                      // hides the prefetch latency
        __syncthreads();                   // drain stage + join readers
        par ^= 1;
    }
    COMPUTE(par);                          // last tile, no prefetch

    // epilogue: denom for q-row col16 lives per-lane; butterfly over quads,
    // then pull denom[quad*4+reg] for the C-layout output rows.
#pragma unroll
    for (int mg = 0; mg < 2; mg++) {
        float l = lsum[mg];
        l += __shfl_xor(l, 16);
        l += __shfl_xor(l, 32);
#pragma unroll
        for (int reg = 0; reg < 4; reg++) {
            float inv = 1.0f / __shfl(l, quad * 4 + reg);
            int nrow = qt * 128 + wave * 32 + mg * 16 + quad * 4 + reg;
            float* op = Out + ((size_t)(b * Nq + nrow)) * DIM + h * DK;
#pragma unroll
            for (int d = 0; d < 4; d++) op[d * 16 + col16] = o[mg][d][reg] * inv;
        }
    }
}

// -------------------------------------------------------------------- launch
extern "C" void kernel_launch(void* const* d_in, const int* in_sizes, int n_in,
                              void* d_out, int out_size, void* d_ws, size_t ws_size,
                              hipStream_t stream) {
    const float* text   = (const float*)d_in[0];
    const float* vision = (const float*)d_in[1];
    const float* n1g = (const float*)d_in[2];
    const float* n1b = (const float*)d_in[3];
    const float* n2g = (const float*)d_in[4];
    const float* n2b = (const float*)d_in[5];
    const float* W[6];
    const float* bias[6];
    for (int i = 0; i < 6; i++) {
        W[i]    = (const float*)d_in[6 + 2 * i];
        bias[i] = (const float*)d_in[7 + 2 * i];
    }

    float* out = (float*)d_out;
    float* a1   = out;                 // (8,512,1024)
    float* a2   = out + 4194304;       // (8,1024,1024)
    float* tres = out + 12582912;      // (8,512,1024)
    float* vres = out + 16777216;      // (8,1024,1024)

    char* ws = (char*)d_ws;
    unsigned short* Wc  = (unsigned short*)(ws);              // 12.0 MB
    unsigned short* tno = (unsigned short*)(ws + 12582912);   //  8.0 MB
    unsigned short* vno = (unsigned short*)(ws + 20971520);   // 16.0 MB
    unsigned short* tq  = (unsigned short*)(ws + 37748736);
    unsigned short* tk  = (unsigned short*)(ws + 46137344);
    unsigned short* tvT = (unsigned short*)(ws + 54525952);   // transposed
    unsigned short* vq  = (unsigned short*)(ws + 62914560);
    unsigned short* vk  = (unsigned short*)(ws + 79691776);
    unsigned short* vvT = (unsigned short*)(ws + 96468992);   // transposed

    WPtrs wp;
    for (int i = 0; i < 6; i++) wp.w[i] = W[i];
    cvt_w_kernel<<<dim3(1024, 6), 256, 0, stream>>>(wp, Wc);
    ln_copy_kernel<<<4096, 256, 0, stream>>>(text, n1g, n1b, tno, tres);
    ln_copy_kernel<<<8192, 256, 0, stream>>>(vision, n2g, n2b, vno, vres);

    GemmParams gp;
    gp.A[0] = tno; gp.A[1] = vno; gp.W = Wc;
    for (int i = 0; i < 6; i++) gp.bias[i] = bias[i];
    gp.out[0] = tq; gp.out[1] = tk; gp.out[2] = tvT;
    gp.out[3] = vq; gp.out[4] = vk; gp.out[5] = vvT;
    gemm_qkv_kernel<<<2304, 256, 0, stream>>>(gp);

    // both cross-attentions in one dispatch (independent jobs, overlap them)
    attn_kernel<<<1536, 256, 0, stream>>>(tq, vk, vvT, a1, vq, tk, tvT, a2);
}

// Round 6
// 311.403 us; speedup vs baseline: 1.3249x; 1.0426x over previous
//
#include <hip/hip_runtime.h>
#include <stdint.h>

// CrossAttention fused pipeline for MI355X (gfx950).
// R10: RECOVERY.  R8/R9's counted-vmcnt attention NaN'd twice; best remaining
//   theory is spill-corrupted vmcnt bookkeeping under the (256,5) VGPR cap
//   (scratch ops count in vmcnt -> static vmcnt(4) no longer means "tile t
//   landed").  Per m152 discipline: revert to the R7 sync structure that
//   PASSED (depth-1 LDS double buffer, ONE __syncthreads per tile, whose
//   vmcnt(0) drain is semantically required anyway for depth-1).
//   Banked from the failed rounds (orthogonal, audited):
//    - prep fusion: cvt_w + both layernorms in one dispatch (2 fewer gaps).
//    - GEMM __launch_bounds__(256,3) (passed in R7 at ~85us).
// R7 kept: fragment-major LDS K/V staging (frag f at base+f*1KB, lane*16B ==
//   the forced-linear global_load_lds dest), sigma-permuted GLOBAL source.
// R6 kept: register-resident softmax via sigma-permuted K rows (QK C-layout
//   IS the PV A-fragment after exp2+cvt_pk), softmax scale folded into Q GEMM.
// R5 kept: both attention directions in one 1536-block dispatch.
// R4 GEMM structure kept (BK=64, XOR-swizzled LDS, XCD m-partition).

#define DIM 1024
#define HEADS 16
#define DK 64
#define BATCH 8
#define NTXT 512
#define NVIS 1024

typedef __attribute__((ext_vector_type(8))) short bf16x8;
typedef __attribute__((ext_vector_type(4))) float f32x4;
typedef __attribute__((ext_vector_type(4))) unsigned short u16x4;
typedef __attribute__((ext_vector_type(4))) unsigned int u32x4;

__device__ inline unsigned short f2bf(float f) {
    unsigned u = __builtin_bit_cast(unsigned, f);
    u += 0x7fffu + ((u >> 16) & 1u);   // round-to-nearest-even
    return (unsigned short)(u >> 16);
}
__device__ inline f32x4 mfma16(bf16x8 a, bf16x8 b, f32x4 c) {
    return __builtin_amdgcn_mfma_f32_16x16x32_bf16(a, b, c, 0, 0, 0);
}
// async global->LDS, 16B per lane. LDS dest = wave-uniform base + lane*16.
__device__ inline void gl_lds16(const unsigned short* gp, unsigned short* lp) {
    const auto* g1 = reinterpret_cast<const __attribute__((address_space(1))) unsigned int*>(
        reinterpret_cast<uintptr_t>(gp));
    auto* l3 = reinterpret_cast<__attribute__((address_space(3))) unsigned int*>(
        reinterpret_cast<uintptr_t>(lp));
    __builtin_amdgcn_global_load_lds(g1, l3, 16, 0, 0);
}

// ------------------------------------------------ prep: weights cvt + 2x LN
// gid [0,6144): convert one 256x4-float slice of a weight matrix to bf16.
// gid [6144,10240): text LN row.  gid [10240,18432): vision LN row.
struct WPtrs { const float* w[6]; };

__global__ __launch_bounds__(256) void prep_kernel(
        WPtrs p, unsigned short* __restrict__ Wc,
        const float* __restrict__ text, const float* __restrict__ n1g,
        const float* __restrict__ n1b, unsigned short* __restrict__ tno,
        float* __restrict__ tres,
        const float* __restrict__ vision, const float* __restrict__ n2g,
        const float* __restrict__ n2b, unsigned short* __restrict__ vno,
        float* __restrict__ vres) {
    int gid = blockIdx.x;
    int tid = threadIdx.x;
    if (gid < 6144) {
        int g = gid >> 10;
        int i = (gid & 1023) * 256 + tid;            // groups of 4 floats
        float4 v = ((const float4*)p.w[g])[i];
        u16x4 o;
        o[0] = f2bf(v.x); o[1] = f2bf(v.y); o[2] = f2bf(v.z); o[3] = f2bf(v.w);
        *(u16x4*)(Wc + (size_t)g * (DIM * DIM) + (size_t)i * 4) = o;
        return;
    }
    const float* x; const float* g; const float* bta;
    unsigned short* xn; float* res; int row;
    if (gid < 10240) { row = gid - 6144;  x = text;   g = n1g; bta = n1b; xn = tno; res = tres; }
    else             { row = gid - 10240; x = vision; g = n2g; bta = n2b; xn = vno; res = vres; }
    const float4* xr = (const float4*)(x + (size_t)row * DIM);
    float4 v = xr[tid];
    float s = v.x + v.y + v.z + v.w;
    float ss = v.x * v.x + v.y * v.y + v.z * v.z + v.w * v.w;
#pragma unroll
    for (int m = 1; m < 64; m <<= 1) { s += __shfl_xor(s, m); ss += __shfl_xor(ss, m); }
    __shared__ float red[8];
    int wave = tid >> 6, lane = tid & 63;
    if (lane == 0) { red[wave] = s; red[4 + wave] = ss; }
    __syncthreads();
    s = red[0] + red[1] + red[2] + red[3];
    ss = red[4] + red[5] + red[6] + red[7];
    float mu = s * (1.0f / DIM);
    float var = ss * (1.0f / DIM) - mu * mu;
    float rinv = rsqrtf(var + 1e-5f);
    float4 gv = ((const float4*)g)[tid];
    float4 bv = ((const float4*)bta)[tid];
    ((float4*)(res + (size_t)row * DIM))[tid] = v;    // residual passthrough
    u16x4 o;
    o[0] = f2bf((v.x - mu) * rinv * gv.x + bv.x);
    o[1] = f2bf((v.y - mu) * rinv * gv.y + bv.y);
    o[2] = f2bf((v.z - mu) * rinv * gv.z + bv.z);
    o[3] = f2bf((v.w - mu) * rinv * gv.w + bv.w);
    *(u16x4*)(xn + (size_t)row * DIM + tid * 4) = o;
}

// -------------------------------------------------------------- fused QKV GEMM
// C[m][n] = sum_k A[m][k] * W[n][k] + bias[n]   (NT layout)
// g in {2,5} (V projections) write TRANSPOSED: Vt[b][h][d][npos]
// g in {0,3} (Q projections) are pre-scaled by (1/8)*log2(e) for softmax.
struct GemmParams {
    const unsigned short* A[2];      // [0]=t_norm (M=4096), [1]=v_norm (M=8192)
    const unsigned short* W;         // 6 contiguous bf16 weight matrices
    const float* bias[6];
    unsigned short* out[6];          // out[2],out[5] are transposed-V buffers
};

__global__ __launch_bounds__(256, 3) void gemm_qkv_kernel(GemmParams P) {
    int bid = blockIdx.x;
    int xcd = bid & 7;
    int idx = bid >> 3;                 // 0..287 per XCD
    int g, tm, tn;
    if (idx < 96) {                     // text: 24 columns x 4 m-tiles
        int col = idx >> 2, mi = idx & 3;
        g = col >> 3; tn = col & 7; tm = xcd * 4 + mi;
    } else {                            // vision: 24 columns x 8 m-tiles
        int j = idx - 96;
        int col = j >> 3, mi = j & 7;
        g = 3 + (col >> 3); tn = col & 7; tm = xcd * 8 + mi;
    }
    const unsigned short* A = P.A[g < 3 ? 0 : 1];
    const unsigned short* Ap = A + (size_t)tm * 128 * DIM;
    const unsigned short* Wp = P.W + (size_t)g * (DIM * DIM) + (size_t)tn * 128 * DIM;

    __shared__ __align__(16) unsigned short As[128][64];
    __shared__ __align__(16) unsigned short Bs[128][64];

    int tid = threadIdx.x;
    int wave = tid >> 6, lane = tid & 63;
    int wm = (wave & 1) * 64, wn = (wave >> 1) * 64;
    int col16 = lane & 15, quad = lane >> 4;

    // staging: 1024 16B-slots per buffer; slot s -> row=s>>3, pos=s&7;
    // global chunk fetched into pos p of row r is c = p ^ (r&7).
    int sbase = wave * 64 + lane;
    size_t ga[4];
    unsigned short* lA[4];
    unsigned short* lB[4];
#pragma unroll
    for (int i = 0; i < 4; i++) {
        int s = sbase + i * 256;
        int row = s >> 3;
        int c = (s & 7) ^ (row & 7);
        ga[i] = (size_t)row * DIM + (size_t)c * 8;
        lA[i] = &As[0][0] + (size_t)s * 8;
        lB[i] = &Bs[0][0] + (size_t)s * 8;
    }

    f32x4 zero = {0.f, 0.f, 0.f, 0.f};
    f32x4 acc[4][4];
#pragma unroll
    for (int i = 0; i < 4; i++)
#pragma unroll
        for (int j = 0; j < 4; j++) acc[i][j] = zero;

    for (int k0 = 0; k0 < DIM; k0 += 64) {
        __syncthreads();                                  // WAR on LDS
#pragma unroll
        for (int i = 0; i < 4; i++) {
            gl_lds16(Ap + ga[i] + k0, lA[i]);
            gl_lds16(Wp + ga[i] + k0, lB[i]);
        }
        __syncthreads();                                  // drain + RAW
#pragma unroll
        for (int ks = 0; ks < 2; ks++) {
            bf16x8 af[4], bfr[4];
#pragma unroll
            for (int mi = 0; mi < 4; mi++) {
                int r = wm + mi * 16 + col16;
                int p = (ks * 4 + quad) ^ (r & 7);
                af[mi] = *(const bf16x8*)&As[r][p * 8];
            }
#pragma unroll
            for (int ni = 0; ni < 4; ni++) {
                int r = wn + ni * 16 + col16;
                int p = (ks * 4 + quad) ^ (r & 7);
                bfr[ni] = *(const bf16x8*)&Bs[r][p * 8];
            }
#pragma unroll
            for (int mi = 0; mi < 4; mi++)
#pragma unroll
                for (int ni = 0; ni < 4; ni++)
                    acc[mi][ni] = mfma16(af[mi], bfr[ni], acc[mi][ni]);
        }
    }

    const float* bias = P.bias[g];
    unsigned short* out = P.out[g];
    // Q projections carry the softmax scale so attention can use raw exp2.
    float qs = (g == 0 || g == 3) ? 0.18033688f : 1.0f;   // (1/8)*log2(e)
    float bv[4];
#pragma unroll
    for (int ni = 0; ni < 4; ni++) bv[ni] = bias[tn * 128 + wn + ni * 16 + col16];

    if (g == 2 || g == 5) {
        int N = (g == 2) ? NTXT : NVIS;
#pragma unroll
        for (int mi = 0; mi < 4; mi++) {
            int row0 = tm * 128 + wm + mi * 16 + quad * 4;
            int b = row0 / N;
            int npos = row0 - b * N;
#pragma unroll
            for (int ni = 0; ni < 4; ni++) {
                int col = tn * 128 + wn + ni * 16 + col16;
                int h = col >> 6, d = col & 63;
                u16x4 pk;
#pragma unroll
                for (int reg = 0; reg < 4; reg++) pk[reg] = f2bf(acc[mi][ni][reg] + bv[ni]);
                *(u16x4*)(out + ((size_t)((b * HEADS + h) * DK + d)) * N + npos) = pk;
            }
        }
    } else {
#pragma unroll
        for (int mi = 0; mi < 4; mi++) {
#pragma unroll
            for (int reg = 0; reg < 4; reg++) {
                int row = tm * 128 + wm + mi * 16 + quad * 4 + reg;
#pragma unroll
                for (int ni = 0; ni < 4; ni++) {
                    out[(size_t)row * DIM + tn * 128 + wn + ni * 16 + col16] =
                        f2bf((acc[mi][ni][reg] + bv[ni]) * qs);
                }
            }
        }
    }
}

// ------------------------------------------------------- flash cross-attention
// ONE dispatch, both directions.  Block = 4 waves x 32 q-rows, one (b,h,qtile).
// K/V staged once per block into LDS, fragment-major, sigma-permuted global
// source.  Depth-1 double buffer, ONE __syncthreads per kv-tile (its vmcnt(0)
// drain is required for depth-1 anyway):
//   STAGE(0,0); sync; loop t: STAGE(par^1, t+1); COMPUTE(par); sync; par^=1
__global__ __launch_bounds__(256, 4) void attn_kernel(
        const unsigned short* __restrict__ Q1, const unsigned short* __restrict__ K1,
        const unsigned short* __restrict__ V1t, float* __restrict__ O1,
        const unsigned short* __restrict__ Q2, const unsigned short* __restrict__ K2,
        const unsigned short* __restrict__ V2t, float* __restrict__ O2) {
    int bid = blockIdx.x;
    const unsigned short* Q; const unsigned short* K; const unsigned short* Vt;
    float* Out; int Nq, Nkv;
    if (bid < 512) { Q = Q1; K = K1; Vt = V1t; Out = O1; Nq = NTXT; Nkv = NVIS; }
    else { bid -= 512; Q = Q2; K = K2; Vt = V2t; Out = O2; Nq = NVIS; Nkv = NTXT; }
    int bh = bid & 127;                 // 128 (b,h) pairs
    int qt = bid >> 7;                  // q-tile of 128 rows
    int b = bh >> 4, h = bh & 15;
    int tid = threadIdx.x;
    int wave = tid >> 6, lane = tid & 63;
    int col16 = lane & 15, quad = lane >> 4;

    // [parity][K=0/V=1][frag 0..7][512 shorts = 1KB]; 32KB total.
    __shared__ __align__(16) unsigned short KV[2][2][8][512];

    const unsigned short* qbase =
        Q + ((size_t)(b * Nq + qt * 128 + wave * 32 + col16)) * DIM + h * DK;
    bf16x8 qa[2][2];
#pragma unroll
    for (int mg = 0; mg < 2; mg++) {
        qa[mg][0] = *(const bf16x8*)(qbase + (size_t)mg * 16 * DIM + quad * 8);
        qa[mg][1] = *(const bf16x8*)(qbase + (size_t)mg * 16 * DIM + 32 + quad * 8);
    }

    // sigma row base for this lane: 8*(col16>>2) + (col16&3)
    int r0 = ((col16 >> 2) << 3) + (col16 & 3);

    // This wave stages K frags {2w,2w+1} and V frags {2w,2w+1}:
    //   K: hh = w>>1, pair = w&1, kh = 0/1
    //   V: hh = w>>1, d = 2*(w&1) + 0/1
    int whh = wave >> 1, wpr = wave & 1;
    const unsigned short* Ksrc =
        K + ((size_t)b * Nkv + 32 * whh + 4 * wpr + r0) * DIM + h * DK + quad * 8;
    const unsigned short* Vsrc =
        Vt + (size_t)(b * HEADS + h) * DK * Nkv
           + (size_t)(2 * wpr * 16 + col16) * Nkv + 32 * whh + quad * 8;
    unsigned short* ldsK0 = &KV[0][0][2 * wave][0];
    unsigned short* ldsK1 = &KV[0][0][2 * wave + 1][0];
    unsigned short* ldsV0 = &KV[0][1][2 * wave][0];
    unsigned short* ldsV1 = &KV[0][1][2 * wave + 1][0];
    const int PSTRIDE = 2 * 8 * 512;    // shorts per parity (16KB)

    f32x4 zero = {0.f, 0.f, 0.f, 0.f};
    f32x4 o[2][4];
#pragma unroll
    for (int mg = 0; mg < 2; mg++)
#pragma unroll
        for (int d = 0; d < 4; d++) o[mg][d] = zero;
    float lsum[2] = {0.f, 0.f};

    auto STAGE = [&](int p, int nb) {
        const unsigned short* ks = Ksrc + (size_t)nb * DIM;
        const unsigned short* vs = Vsrc + nb;
        int po = p * PSTRIDE;
        gl_lds16(ks,            ldsK0 + po);
        gl_lds16(ks + 32,       ldsK1 + po);
        gl_lds16(vs,            ldsV0 + po);
        gl_lds16(vs + 16 * Nkv, ldsV1 + po);
    };

    auto COMPUTE = [&](int p) {
        const unsigned short* base = &KV[p][0][0][0] + lane * 8;
#pragma unroll
        for (int hh = 0; hh < 2; hh++) {
            bf16x8 ka0 = *(const bf16x8*)(base + (hh * 4 + 0) * 512);
            bf16x8 ka1 = *(const bf16x8*)(base + (hh * 4 + 1) * 512);
            bf16x8 kb0 = *(const bf16x8*)(base + (hh * 4 + 2) * 512);
            bf16x8 kb1 = *(const bf16x8*)(base + (hh * 4 + 3) * 512);
            bf16x8 vf[4];
#pragma unroll
            for (int d = 0; d < 4; d++)
                vf[d] = *(const bf16x8*)(base + 4096 + (hh * 4 + d) * 512);
#pragma unroll
            for (int mg = 0; mg < 2; mg++) {
                f32x4 ca = zero, cb = zero;
                ca = mfma16(ka0, qa[mg][0], ca);
                ca = mfma16(ka1, qa[mg][1], ca);
                cb = mfma16(kb0, qa[mg][0], cb);
                cb = mfma16(kb1, qa[mg][1], cb);
                float p0 = __builtin_amdgcn_exp2f(ca[0]);
                float p1 = __builtin_amdgcn_exp2f(ca[1]);
                float p2 = __builtin_amdgcn_exp2f(ca[2]);
                float p3 = __builtin_amdgcn_exp2f(ca[3]);
                float p4 = __builtin_amdgcn_exp2f(cb[0]);
                float p5 = __builtin_amdgcn_exp2f(cb[1]);
                float p6 = __builtin_amdgcn_exp2f(cb[2]);
                float p7 = __builtin_amdgcn_exp2f(cb[3]);
                lsum[mg] += ((p0 + p1) + (p2 + p3)) + ((p4 + p5) + (p6 + p7));
                unsigned int w0, w1, w2, w3;
                asm("v_cvt_pk_bf16_f32 %0, %1, %2" : "=v"(w0) : "v"(p0), "v"(p1));
                asm("v_cvt_pk_bf16_f32 %0, %1, %2" : "=v"(w1) : "v"(p2), "v"(p3));
                asm("v_cvt_pk_bf16_f32 %0, %1, %2" : "=v"(w2) : "v"(p4), "v"(p5));
                asm("v_cvt_pk_bf16_f32 %0, %1, %2" : "=v"(w3) : "v"(p6), "v"(p7));
                u32x4 pw = {w0, w1, w2, w3};
                bf16x8 pf = __builtin_bit_cast(bf16x8, pw);
#pragma unroll
                for (int d = 0; d < 4; d++) o[mg][d] = mfma16(pf, vf[d], o[mg][d]);
            }
        }
    };

    int NT = Nkv >> 6;
    STAGE(0, 0);
    __syncthreads();                       // drain prologue stage
    int par = 0;
    for (int t = 0; t + 1 < NT; t++) {
        STAGE(par ^ 1, (t + 1) << 6);      // prefetch next tile (async)
        COMPUTE(par);                      // hides the prefetch latency
        __syncthreads();                   // drain stage + join readers
        par ^= 1;
    }
    COMPUTE(par);                          // last tile, no prefetch

    // epilogue: denom for q-row col16 lives per-lane; butterfly over quads,
    // then pull denom[quad*4+reg] for the C-layout output rows.
#pragma unroll
    for (int mg = 0; mg < 2; mg++) {
        float l = lsum[mg];
        l += __shfl_xor(l, 16);
        l += __shfl_xor(l, 32);
#pragma unroll
        for (int reg = 0; reg < 4; reg++) {
            float inv = 1.0f / __shfl(l, quad * 4 + reg);
            int nrow = qt * 128 + wave * 32 + mg * 16 + quad * 4 + reg;
            float* op = Out + ((size_t)(b * Nq + nrow)) * DIM + h * DK;
#pragma unroll
            for (int d = 0; d < 4; d++) op[d * 16 + col16] = o[mg][d][reg] * inv;
        }
    }
}

// -------------------------------------------------------------------- launch
extern "C" void kernel_launch(void* const* d_in, const int* in_sizes, int n_in,
                              void* d_out, int out_size, void* d_ws, size_t ws_size,
                              hipStream_t stream) {
    const float* text   = (const float*)d_in[0];
    const float* vision = (const float*)d_in[1];
    const float* n1g = (const float*)d_in[2];
    const float* n1b = (const float*)d_in[3];
    const float* n2g = (const float*)d_in[4];
    const float* n2b = (const float*)d_in[5];
    const float* W[6];
    const float* bias[6];
    for (int i = 0; i < 6; i++) {
        W[i]    = (const float*)d_in[6 + 2 * i];
        bias[i] = (const float*)d_in[7 + 2 * i];
    }

    float* out = (float*)d_out;
    float* a1   = out;                 // (8,512,1024)
    float* a2   = out + 4194304;       // (8,1024,1024)
    float* tres = out + 12582912;      // (8,512,1024)
    float* vres = out + 16777216;      // (8,1024,1024)

    char* ws = (char*)d_ws;
    unsigned short* Wc  = (unsigned short*)(ws);              // 12.0 MB
    unsigned short* tno = (unsigned short*)(ws + 12582912);   //  8.0 MB
    unsigned short* vno = (unsigned short*)(ws + 20971520);   // 16.0 MB
    unsigned short* tq  = (unsigned short*)(ws + 37748736);
    unsigned short* tk  = (unsigned short*)(ws + 46137344);
    unsigned short* tvT = (unsigned short*)(ws + 54525952);   // transposed
    unsigned short* vq  = (unsigned short*)(ws + 62914560);
    unsigned short* vk  = (unsigned short*)(ws + 79691776);
    unsigned short* vvT = (unsigned short*)(ws + 96468992);   // transposed

    WPtrs wp;
    for (int i = 0; i < 6; i++) wp.w[i] = W[i];
    prep_kernel<<<18432, 256, 0, stream>>>(wp, Wc,
                                           text, n1g, n1b, tno, tres,
                                           vision, n2g, n2b, vno, vres);

    GemmParams gp;
    gp.A[0] = tno; gp.A[1] = vno; gp.W = Wc;
    for (int i = 0; i < 6; i++) gp.bias[i] = bias[i];
    gp.out[0] = tq; gp.out[1] = tk; gp.out[2] = tvT;
    gp.out[3] = vq; gp.out[4] = vk; gp.out[5] = vvT;
    gemm_qkv_kernel<<<2304, 256, 0, stream>>>(gp);

    // both cross-attentions in one dispatch (independent jobs, overlap them)
    attn_kernel<<<1536, 256, 0, stream>>>(tq, vk, vvT, a1, vq, tk, tvT, a2);
}

// Round 7
// 310.940 us; speedup vs baseline: 1.3268x; 1.0015x over previous
//
#include <hip/hip_runtime.h>
#include <stdint.h>

// CrossAttention fused pipeline for MI355X (gfx950).
// R11: reg-staged depth-2 attention prefetch (T14 async-STAGE split) using
//   ONLY standard semantics (no raw barriers / hand vmcnt -- the R8/R9 family
//   NaN'd twice and is retired per m152 discipline).
//   Per iter t:  WRITE regs(tile t+1) -> LDS[par^1]   (ds_write_b128 x4)
//                LOADR tile t+2 -> regs               (global_load x4, issued
//                                                      ~a full COMPUTE before
//                                                      the barrier drain)
//                COMPUTE(LDS[par]); __syncthreads()
//   The barrier's vmcnt(0) drain now happens ~600 cyc after the t+2 loads
//   were issued -> latency hidden; effective pipeline depth 2.
//   Compiler inserts all waitcnts (loads->ds_write, barrier) => race-free.
// R10 kept: depth-1-style LDS layout (frag-major, sigma-permuted global src),
//   prep fusion, GEMM (256,3) at its structure ceiling (~82us).
// R6 kept: register-resident softmax, softmax scale folded into Q GEMM.

#define DIM 1024
#define HEADS 16
#define DK 64
#define BATCH 8
#define NTXT 512
#define NVIS 1024

typedef __attribute__((ext_vector_type(8))) short bf16x8;
typedef __attribute__((ext_vector_type(4))) float f32x4;
typedef __attribute__((ext_vector_type(4))) unsigned short u16x4;
typedef __attribute__((ext_vector_type(4))) unsigned int u32x4;

__device__ inline unsigned short f2bf(float f) {
    unsigned u = __builtin_bit_cast(unsigned, f);
    u += 0x7fffu + ((u >> 16) & 1u);   // round-to-nearest-even
    return (unsigned short)(u >> 16);
}
__device__ inline f32x4 mfma16(bf16x8 a, bf16x8 b, f32x4 c) {
    return __builtin_amdgcn_mfma_f32_16x16x32_bf16(a, b, c, 0, 0, 0);
}
// async global->LDS, 16B per lane. LDS dest = wave-uniform base + lane*16.
__device__ inline void gl_lds16(const unsigned short* gp, unsigned short* lp) {
    const auto* g1 = reinterpret_cast<const __attribute__((address_space(1))) unsigned int*>(
        reinterpret_cast<uintptr_t>(gp));
    auto* l3 = reinterpret_cast<__attribute__((address_space(3))) unsigned int*>(
        reinterpret_cast<uintptr_t>(lp));
    __builtin_amdgcn_global_load_lds(g1, l3, 16, 0, 0);
}

// ------------------------------------------------ prep: weights cvt + 2x LN
// gid [0,6144): convert one 256x4-float slice of a weight matrix to bf16.
// gid [6144,10240): text LN row.  gid [10240,18432): vision LN row.
struct WPtrs { const float* w[6]; };

__global__ __launch_bounds__(256) void prep_kernel(
        WPtrs p, unsigned short* __restrict__ Wc,
        const float* __restrict__ text, const float* __restrict__ n1g,
        const float* __restrict__ n1b, unsigned short* __restrict__ tno,
        float* __restrict__ tres,
        const float* __restrict__ vision, const float* __restrict__ n2g,
        const float* __restrict__ n2b, unsigned short* __restrict__ vno,
        float* __restrict__ vres) {
    int gid = blockIdx.x;
    int tid = threadIdx.x;
    if (gid < 6144) {
        int g = gid >> 10;
        int i = (gid & 1023) * 256 + tid;            // groups of 4 floats
        float4 v = ((const float4*)p.w[g])[i];
        u16x4 o;
        o[0] = f2bf(v.x); o[1] = f2bf(v.y); o[2] = f2bf(v.z); o[3] = f2bf(v.w);
        *(u16x4*)(Wc + (size_t)g * (DIM * DIM) + (size_t)i * 4) = o;
        return;
    }
    const float* x; const float* g; const float* bta;
    unsigned short* xn; float* res; int row;
    if (gid < 10240) { row = gid - 6144;  x = text;   g = n1g; bta = n1b; xn = tno; res = tres; }
    else             { row = gid - 10240; x = vision; g = n2g; bta = n2b; xn = vno; res = vres; }
    const float4* xr = (const float4*)(x + (size_t)row * DIM);
    float4 v = xr[tid];
    float s = v.x + v.y + v.z + v.w;
    float ss = v.x * v.x + v.y * v.y + v.z * v.z + v.w * v.w;
#pragma unroll
    for (int m = 1; m < 64; m <<= 1) { s += __shfl_xor(s, m); ss += __shfl_xor(ss, m); }
    __shared__ float red[8];
    int wave = tid >> 6, lane = tid & 63;
    if (lane == 0) { red[wave] = s; red[4 + wave] = ss; }
    __syncthreads();
    s = red[0] + red[1] + red[2] + red[3];
    ss = red[4] + red[5] + red[6] + red[7];
    float mu = s * (1.0f / DIM);
    float var = ss * (1.0f / DIM) - mu * mu;
    float rinv = rsqrtf(var + 1e-5f);
    float4 gv = ((const float4*)g)[tid];
    float4 bv = ((const float4*)bta)[tid];
    ((float4*)(res + (size_t)row * DIM))[tid] = v;    // residual passthrough
    u16x4 o;
    o[0] = f2bf((v.x - mu) * rinv * gv.x + bv.x);
    o[1] = f2bf((v.y - mu) * rinv * gv.y + bv.y);
    o[2] = f2bf((v.z - mu) * rinv * gv.z + bv.z);
    o[3] = f2bf((v.w - mu) * rinv * gv.w + bv.w);
    *(u16x4*)(xn + (size_t)row * DIM + tid * 4) = o;
}

// -------------------------------------------------------------- fused QKV GEMM
// C[m][n] = sum_k A[m][k] * W[n][k] + bias[n]   (NT layout)
// g in {2,5} (V projections) write TRANSPOSED: Vt[b][h][d][npos]
// g in {0,3} (Q projections) are pre-scaled by (1/8)*log2(e) for softmax.
struct GemmParams {
    const unsigned short* A[2];      // [0]=t_norm (M=4096), [1]=v_norm (M=8192)
    const unsigned short* W;         // 6 contiguous bf16 weight matrices
    const float* bias[6];
    unsigned short* out[6];          // out[2],out[5] are transposed-V buffers
};

__global__ __launch_bounds__(256, 3) void gemm_qkv_kernel(GemmParams P) {
    int bid = blockIdx.x;
    int xcd = bid & 7;
    int idx = bid >> 3;                 // 0..287 per XCD
    int g, tm, tn;
    if (idx < 96) {                     // text: 24 columns x 4 m-tiles
        int col = idx >> 2, mi = idx & 3;
        g = col >> 3; tn = col & 7; tm = xcd * 4 + mi;
    } else {                            // vision: 24 columns x 8 m-tiles
        int j = idx - 96;
        int col = j >> 3, mi = j & 7;
        g = 3 + (col >> 3); tn = col & 7; tm = xcd * 8 + mi;
    }
    const unsigned short* A = P.A[g < 3 ? 0 : 1];
    const unsigned short* Ap = A + (size_t)tm * 128 * DIM;
    const unsigned short* Wp = P.W + (size_t)g * (DIM * DIM) + (size_t)tn * 128 * DIM;

    __shared__ __align__(16) unsigned short As[128][64];
    __shared__ __align__(16) unsigned short Bs[128][64];

    int tid = threadIdx.x;
    int wave = tid >> 6, lane = tid & 63;
    int wm = (wave & 1) * 64, wn = (wave >> 1) * 64;
    int col16 = lane & 15, quad = lane >> 4;

    // staging: 1024 16B-slots per buffer; slot s -> row=s>>3, pos=s&7;
    // global chunk fetched into pos p of row r is c = p ^ (r&7).
    int sbase = wave * 64 + lane;
    size_t ga[4];
    unsigned short* lA[4];
    unsigned short* lB[4];
#pragma unroll
    for (int i = 0; i < 4; i++) {
        int s = sbase + i * 256;
        int row = s >> 3;
        int c = (s & 7) ^ (row & 7);
        ga[i] = (size_t)row * DIM + (size_t)c * 8;
        lA[i] = &As[0][0] + (size_t)s * 8;
        lB[i] = &Bs[0][0] + (size_t)s * 8;
    }

    f32x4 zero = {0.f, 0.f, 0.f, 0.f};
    f32x4 acc[4][4];
#pragma unroll
    for (int i = 0; i < 4; i++)
#pragma unroll
        for (int j = 0; j < 4; j++) acc[i][j] = zero;

    for (int k0 = 0; k0 < DIM; k0 += 64) {
        __syncthreads();                                  // WAR on LDS
#pragma unroll
        for (int i = 0; i < 4; i++) {
            gl_lds16(Ap + ga[i] + k0, lA[i]);
            gl_lds16(Wp + ga[i] + k0, lB[i]);
        }
        __syncthreads();                                  // drain + RAW
#pragma unroll
        for (int ks = 0; ks < 2; ks++) {
            bf16x8 af[4], bfr[4];
#pragma unroll
            for (int mi = 0; mi < 4; mi++) {
                int r = wm + mi * 16 + col16;
                int p = (ks * 4 + quad) ^ (r & 7);
                af[mi] = *(const bf16x8*)&As[r][p * 8];
            }
#pragma unroll
            for (int ni = 0; ni < 4; ni++) {
                int r = wn + ni * 16 + col16;
                int p = (ks * 4 + quad) ^ (r & 7);
                bfr[ni] = *(const bf16x8*)&Bs[r][p * 8];
            }
#pragma unroll
            for (int mi = 0; mi < 4; mi++)
#pragma unroll
                for (int ni = 0; ni < 4; ni++)
                    acc[mi][ni] = mfma16(af[mi], bfr[ni], acc[mi][ni]);
        }
    }

    const float* bias = P.bias[g];
    unsigned short* out = P.out[g];
    // Q projections carry the softmax scale so attention can use raw exp2.
    float qs = (g == 0 || g == 3) ? 0.18033688f : 1.0f;   // (1/8)*log2(e)
    float bv[4];
#pragma unroll
    for (int ni = 0; ni < 4; ni++) bv[ni] = bias[tn * 128 + wn + ni * 16 + col16];

    if (g == 2 || g == 5) {
        int N = (g == 2) ? NTXT : NVIS;
#pragma unroll
        for (int mi = 0; mi < 4; mi++) {
            int row0 = tm * 128 + wm + mi * 16 + quad * 4;
            int b = row0 / N;
            int npos = row0 - b * N;
#pragma unroll
            for (int ni = 0; ni < 4; ni++) {
                int col = tn * 128 + wn + ni * 16 + col16;
                int h = col >> 6, d = col & 63;
                u16x4 pk;
#pragma unroll
                for (int reg = 0; reg < 4; reg++) pk[reg] = f2bf(acc[mi][ni][reg] + bv[ni]);
                *(u16x4*)(out + ((size_t)((b * HEADS + h) * DK + d)) * N + npos) = pk;
            }
        }
    } else {
#pragma unroll
        for (int mi = 0; mi < 4; mi++) {
#pragma unroll
            for (int reg = 0; reg < 4; reg++) {
                int row = tm * 128 + wm + mi * 16 + quad * 4 + reg;
#pragma unroll
                for (int ni = 0; ni < 4; ni++) {
                    out[(size_t)row * DIM + tn * 128 + wn + ni * 16 + col16] =
                        f2bf((acc[mi][ni][reg] + bv[ni]) * qs);
                }
            }
        }
    }
}

// ------------------------------------------------------- flash cross-attention
// ONE dispatch, both directions.  Block = 4 waves x 32 q-rows, one (b,h,qtile).
// K/V staged per block into LDS (frag-major, sigma-permuted GLOBAL source).
// R11 schedule (reg-staged depth-2, standard semantics only):
//   prologue: LOADR(0); WRITE(par0); LOADR(1); __syncthreads()
//   iter t:   [WRITE(par^1) = tile t+1]  [LOADR(t+2)]  COMPUTE(par); sync
// The t+2 global loads are issued a full COMPUTE before the barrier's
// vmcnt(0) drain -> latency hidden.  ds_write waits (loads are 1 iter old)
// and barrier ordering are all compiler-managed.
__global__ __launch_bounds__(256, 4) void attn_kernel(
        const unsigned short* __restrict__ Q1, const unsigned short* __restrict__ K1,
        const unsigned short* __restrict__ V1t, float* __restrict__ O1,
        const unsigned short* __restrict__ Q2, const unsigned short* __restrict__ K2,
        const unsigned short* __restrict__ V2t, float* __restrict__ O2) {
    int bid = blockIdx.x;
    const unsigned short* Q; const unsigned short* K; const unsigned short* Vt;
    float* Out; int Nq, Nkv;
    if (bid < 512) { Q = Q1; K = K1; Vt = V1t; Out = O1; Nq = NTXT; Nkv = NVIS; }
    else { bid -= 512; Q = Q2; K = K2; Vt = V2t; Out = O2; Nq = NVIS; Nkv = NTXT; }
    int bh = bid & 127;                 // 128 (b,h) pairs
    int qt = bid >> 7;                  // q-tile of 128 rows
    int b = bh >> 4, h = bh & 15;
    int tid = threadIdx.x;
    int wave = tid >> 6, lane = tid & 63;
    int col16 = lane & 15, quad = lane >> 4;

    // [parity][K=0/V=1][frag 0..7][512 shorts = 1KB]; 32KB total.
    __shared__ __align__(16) unsigned short KV[2][2][8][512];

    const unsigned short* qbase =
        Q + ((size_t)(b * Nq + qt * 128 + wave * 32 + col16)) * DIM + h * DK;
    bf16x8 qa[2][2];
#pragma unroll
    for (int mg = 0; mg < 2; mg++) {
        qa[mg][0] = *(const bf16x8*)(qbase + (size_t)mg * 16 * DIM + quad * 8);
        qa[mg][1] = *(const bf16x8*)(qbase + (size_t)mg * 16 * DIM + 32 + quad * 8);
    }

    // sigma row base for this lane: 8*(col16>>2) + (col16&3)
    int r0 = ((col16 >> 2) << 3) + (col16 & 3);

    // This wave owns K frags {2w,2w+1} and V frags {2w,2w+1}:
    //   K: hh = w>>1, pair = w&1, kh = 0/1
    //   V: hh = w>>1, d = 2*(w&1) + 0/1
    int whh = wave >> 1, wpr = wave & 1;
    const unsigned short* Ksrc =
        K + ((size_t)b * Nkv + 32 * whh + 4 * wpr + r0) * DIM + h * DK + quad * 8;
    const unsigned short* Vsrc =
        Vt + (size_t)(b * HEADS + h) * DK * Nkv
           + (size_t)(2 * wpr * 16 + col16) * Nkv + 32 * whh + quad * 8;
    unsigned short* ldsK0 = &KV[0][0][2 * wave][0] + (size_t)lane * 8;
    unsigned short* ldsK1 = &KV[0][0][2 * wave + 1][0] + (size_t)lane * 8;
    unsigned short* ldsV0 = &KV[0][1][2 * wave][0] + (size_t)lane * 8;
    unsigned short* ldsV1 = &KV[0][1][2 * wave + 1][0] + (size_t)lane * 8;
    const int PSTRIDE = 2 * 8 * 512;    // shorts per parity (16KB)

    f32x4 zero = {0.f, 0.f, 0.f, 0.f};
    f32x4 o[2][4];
#pragma unroll
    for (int mg = 0; mg < 2; mg++)
#pragma unroll
        for (int d = 0; d < 4; d++) o[mg][d] = zero;
    float lsum[2] = {0.f, 0.f};

    // register staging buffer: one kv-tile (4 x 16B per lane)
    bf16x8 rk0, rk1, rv0, rv1;

    auto LOADR = [&](int t) {
        const unsigned short* ks = Ksrc + (((size_t)t) << 6) * DIM;
        const unsigned short* vs = Vsrc + (t << 6);
        rk0 = *(const bf16x8*)(ks);
        rk1 = *(const bf16x8*)(ks + 32);
        rv0 = *(const bf16x8*)(vs);
        rv1 = *(const bf16x8*)(vs + 16 * Nkv);
    };
    auto WRITE = [&](int p) {
        int po = p * PSTRIDE;
        *(bf16x8*)(ldsK0 + po) = rk0;
        *(bf16x8*)(ldsK1 + po) = rk1;
        *(bf16x8*)(ldsV0 + po) = rv0;
        *(bf16x8*)(ldsV1 + po) = rv1;
    };

    auto COMPUTE = [&](int p) {
        const unsigned short* base = &KV[p][0][0][0] + lane * 8;
#pragma unroll
        for (int hh = 0; hh < 2; hh++) {
            bf16x8 ka0 = *(const bf16x8*)(base + (hh * 4 + 0) * 512);
            bf16x8 ka1 = *(const bf16x8*)(base + (hh * 4 + 1) * 512);
            bf16x8 kb0 = *(const bf16x8*)(base + (hh * 4 + 2) * 512);
            bf16x8 kb1 = *(const bf16x8*)(base + (hh * 4 + 3) * 512);
            bf16x8 vf[4];
#pragma unroll
            for (int d = 0; d < 4; d++)
                vf[d] = *(const bf16x8*)(base + 4096 + (hh * 4 + d) * 512);
#pragma unroll
            for (int mg = 0; mg < 2; mg++) {
                f32x4 ca = zero, cb = zero;
                ca = mfma16(ka0, qa[mg][0], ca);
                ca = mfma16(ka1, qa[mg][1], ca);
                cb = mfma16(kb0, qa[mg][0], cb);
                cb = mfma16(kb1, qa[mg][1], cb);
                float p0 = __builtin_amdgcn_exp2f(ca[0]);
                float p1 = __builtin_amdgcn_exp2f(ca[1]);
                float p2 = __builtin_amdgcn_exp2f(ca[2]);
                float p3 = __builtin_amdgcn_exp2f(ca[3]);
                float p4 = __builtin_amdgcn_exp2f(cb[0]);
                float p5 = __builtin_amdgcn_exp2f(cb[1]);
                float p6 = __builtin_amdgcn_exp2f(cb[2]);
                float p7 = __builtin_amdgcn_exp2f(cb[3]);
                lsum[mg] += ((p0 + p1) + (p2 + p3)) + ((p4 + p5) + (p6 + p7));
                unsigned int w0, w1, w2, w3;
                asm("v_cvt_pk_bf16_f32 %0, %1, %2" : "=v"(w0) : "v"(p0), "v"(p1));
                asm("v_cvt_pk_bf16_f32 %0, %1, %2" : "=v"(w1) : "v"(p2), "v"(p3));
                asm("v_cvt_pk_bf16_f32 %0, %1, %2" : "=v"(w2) : "v"(p4), "v"(p5));
                asm("v_cvt_pk_bf16_f32 %0, %1, %2" : "=v"(w3) : "v"(p6), "v"(p7));
                u32x4 pw = {w0, w1, w2, w3};
                bf16x8 pf = __builtin_bit_cast(bf16x8, pw);
#pragma unroll
                for (int d = 0; d < 4; d++) o[mg][d] = mfma16(pf, vf[d], o[mg][d]);
            }
        }
    };

    int NT = Nkv >> 6;
    LOADR(0);
    WRITE(0);                               // tile 0 -> parity 0
    LOADR(1);                               // tile 1 -> regs (in flight)
    __syncthreads();                        // parity 0 visible to all waves
    int par = 0;
    for (int t = 0; t < NT; t++) {
        if (t + 1 < NT) {
            WRITE(par ^ 1);                 // tile t+1 -> other parity
            if (t + 2 < NT) LOADR(t + 2);   // prefetch t+2 (hides under COMPUTE)
        }
        COMPUTE(par);
        if (t + 1 < NT) __syncthreads();    // join readers + publish writes
        par ^= 1;
    }

    // epilogue: denom for q-row col16 lives per-lane; butterfly over quads,
    // then pull denom[quad*4+reg] for the C-layout output rows.
#pragma unroll
    for (int mg = 0; mg < 2; mg++) {
        float l = lsum[mg];
        l += __shfl_xor(l, 16);
        l += __shfl_xor(l, 32);
#pragma unroll
        for (int reg = 0; reg < 4; reg++) {
            float inv = 1.0f / __shfl(l, quad * 4 + reg);
            int nrow = qt * 128 + wave * 32 + mg * 16 + quad * 4 + reg;
            float* op = Out + ((size_t)(b * Nq + nrow)) * DIM + h * DK;
#pragma unroll
            for (int d = 0; d < 4; d++) op[d * 16 + col16] = o[mg][d][reg] * inv;
        }
    }
}

// -------------------------------------------------------------------- launch
extern "C" void kernel_launch(void* const* d_in, const int* in_sizes, int n_in,
                              void* d_out, int out_size, void* d_ws, size_t ws_size,
                              hipStream_t stream) {
    const float* text   = (const float*)d_in[0];
    const float* vision = (const float*)d_in[1];
    const float* n1g = (const float*)d_in[2];
    const float* n1b = (const float*)d_in[3];
    const float* n2g = (const float*)d_in[4];
    const float* n2b = (const float*)d_in[5];
    const float* W[6];
    const float* bias[6];
    for (int i = 0; i < 6; i++) {
        W[i]    = (const float*)d_in[6 + 2 * i];
        bias[i] = (const float*)d_in[7 + 2 * i];
    }

    float* out = (float*)d_out;
    float* a1   = out;                 // (8,512,1024)
    float* a2   = out + 4194304;       // (8,1024,1024)
    float* tres = out + 12582912;      // (8,512,1024)
    float* vres = out + 16777216;      // (8,1024,1024)

    char* ws = (char*)d_ws;
    unsigned short* Wc  = (unsigned short*)(ws);              // 12.0 MB
    unsigned short* tno = (unsigned short*)(ws + 12582912);   //  8.0 MB
    unsigned short* vno = (unsigned short*)(ws + 20971520);   // 16.0 MB
    unsigned short* tq  = (unsigned short*)(ws + 37748736);
    unsigned short* tk  = (unsigned short*)(ws + 46137344);
    unsigned short* tvT = (unsigned short*)(ws + 54525952);   // transposed
    unsigned short* vq  = (unsigned short*)(ws + 62914560);
    unsigned short* vk  = (unsigned short*)(ws + 79691776);
    unsigned short* vvT = (unsigned short*)(ws + 96468992);   // transposed

    WPtrs wp;
    for (int i = 0; i < 6; i++) wp.w[i] = W[i];
    prep_kernel<<<18432, 256, 0, stream>>>(wp, Wc,
                                           text, n1g, n1b, tno, tres,
                                           vision, n2g, n2b, vno, vres);

    GemmParams gp;
    gp.A[0] = tno; gp.A[1] = vno; gp.W = Wc;
    for (int i = 0; i < 6; i++) gp.bias[i] = bias[i];
    gp.out[0] = tq; gp.out[1] = tk; gp.out[2] = tvT;
    gp.out[3] = vq; gp.out[4] = vk; gp.out[5] = vvT;
    gemm_qkv_kernel<<<2304, 256, 0, stream>>>(gp);

    // both cross-attentions in one dispatch (independent jobs, overlap them)
    attn_kernel<<<1536, 256, 0, stream>>>(tq, vk, vvT, a1, vq, tk, tvT, a2);
}